// Round 1
// baseline (1759.363 us; speedup 1.0000x reference)
//
#include <hip/hip_runtime.h>

#define BB 4
#define CC 256
#define NPIX 4096
#define NG 32
#define CPG 8
#define EPS 1e-6f

__device__ __forceinline__ unsigned short f2bf(float f) {
    return (unsigned short)((__float_as_uint(f) + 0x8000u) >> 16);
}
__device__ __forceinline__ float bf2f(unsigned short h) {
    return __uint_as_float((unsigned)h << 16);
}

// ---------------- Kernel 1: GroupNorm statistics ----------------
__global__ __launch_bounds__(256) void gn_stats(const float* __restrict__ x,
                                                float* __restrict__ meanv,
                                                float* __restrict__ rstdv) {
    int bg = blockIdx.x;            // b*NG + g
    int b = bg >> 5, g = bg & 31;
    const float4* xb4 = (const float4*)(x + (size_t)(b * CC + g * CPG) * NPIX);
    float s = 0.f, ss = 0.f;
    for (int e = threadIdx.x; e < CPG * NPIX / 4; e += 256) {
        float4 v = xb4[e];
        s += v.x + v.y + v.z + v.w;
        ss += v.x * v.x + v.y * v.y + v.z * v.z + v.w * v.w;
    }
    __shared__ float rs[256], rss[256];
    rs[threadIdx.x] = s; rss[threadIdx.x] = ss;
    __syncthreads();
    for (int off = 128; off > 0; off >>= 1) {
        if (threadIdx.x < (unsigned)off) {
            rs[threadIdx.x] += rs[threadIdx.x + off];
            rss[threadIdx.x] += rss[threadIdx.x + off];
        }
        __syncthreads();
    }
    if (threadIdx.x == 0) {
        const float inv = 1.0f / (float)(CPG * NPIX);
        float m = rs[0] * inv;
        float var = rss[0] * inv - m * m;
        meanv[bg] = m;
        rstdv[bg] = rsqrtf(var + EPS);
    }
}

// ---------------- Kernel 2: fused GroupNorm-apply + QKV 1x1 convs ----------------
__global__ __launch_bounds__(256) void qkv_gemm(
    const float* __restrict__ x, const float* __restrict__ meanv,
    const float* __restrict__ rstdv, const float* __restrict__ gamma,
    const float* __restrict__ beta,
    const float* __restrict__ wq, const float* __restrict__ bq,
    const float* __restrict__ wk, const float* __restrict__ bk,
    const float* __restrict__ wv, const float* __restrict__ bv,
    float* __restrict__ qb, float* __restrict__ kb, float* __restrict__ vb) {
    const int tid = threadIdx.x;
    const int n0 = blockIdx.x * 64;
    const int which = blockIdx.y >> 3;
    const int m = blockIdx.y & 7;
    const int b = blockIdx.z;
    const float* w    = (which == 0) ? wq : (which == 1) ? wk : wv;
    const float* bias = (which == 0) ? bq : (which == 1) ? bk : bv;
    float* outp       = (which == 0) ? qb : (which == 1) ? kb : vb;

    __shared__ float sS[32][64];
    __shared__ float sW[32][33];

    const int px4 = (tid & 15) << 2;
    const int ob = tid >> 4;   // 0..15 -> 2 output rows each
    float4 acc0 = {0, 0, 0, 0}, acc1 = {0, 0, 0, 0};

    for (int kt = 0; kt < 8; ++kt) {
#pragma unroll
        for (int r = 0; r < 8; ++r) {
            int e = tid + r * 256;
            int ci = e >> 6, pxl = e & 63;
            int c = kt * 32 + ci;
            int bg = b * 32 + (c >> 3);
            float v = x[(size_t)(b * CC + c) * NPIX + n0 + pxl];
            sS[ci][pxl] = (v - meanv[bg]) * rstdv[bg] * gamma[c] + beta[c];
        }
#pragma unroll
        for (int r = 0; r < 4; ++r) {
            int e = tid + r * 256;
            int o = e >> 5, i = e & 31;
            sW[o][i] = w[(size_t)(m * 32 + o) * CC + kt * 32 + i];
        }
        __syncthreads();
#pragma unroll 8
        for (int kk = 0; kk < 32; ++kk) {
            float4 sv = *(const float4*)&sS[kk][px4];
            float w0 = sW[ob * 2 + 0][kk];
            float w1 = sW[ob * 2 + 1][kk];
            acc0.x += w0 * sv.x; acc0.y += w0 * sv.y;
            acc0.z += w0 * sv.z; acc0.w += w0 * sv.w;
            acc1.x += w1 * sv.x; acc1.y += w1 * sv.y;
            acc1.z += w1 * sv.z; acc1.w += w1 * sv.w;
        }
        __syncthreads();
    }
    int o0 = m * 32 + ob * 2;
    float b0 = bias[o0], b1 = bias[o0 + 1];
    float4 r0 = {acc0.x + b0, acc0.y + b0, acc0.z + b0, acc0.w + b0};
    float4 r1 = {acc1.x + b1, acc1.y + b1, acc1.z + b1, acc1.w + b1};
    *(float4*)(outp + (size_t)(b * CC + o0) * NPIX + n0 + px4) = r0;
    *(float4*)(outp + (size_t)(b * CC + o0 + 1) * NPIX + n0 + px4) = r1;
}

// ---------------- Kernel 3: flash attention (online softmax) ----------------
// One block per (batch, 32-query tile). bf16 tiles in LDS, fp32 accumulate.
__global__ __launch_bounds__(256, 2) void attn_flash(
    const float* __restrict__ qb, const float* __restrict__ kb,
    const float* __restrict__ vb, float* __restrict__ hb) {
    const int tid = threadIdx.x;
    const int i0 = blockIdx.x * 32;
    const int b = blockIdx.y;
    const float* qp = qb + (size_t)b * CC * NPIX;
    const float* kp = kb + (size_t)b * CC * NPIX;
    const float* vp = vb + (size_t)b * CC * NPIX;

    __shared__ unsigned short qs[256][32];   // [c][i], q pre-scaled by C^-1/2
    __shared__ unsigned short ks[256][32];   // [c][j]
    __shared__ union U {
        float ps4[4][32][36];                // per-c-slice score partials
        unsigned short vs[32][264];          // [j][c] V tile (staged after softmax)
    } u;
    __shared__ float ps[32][33];             // P = exp(s - m)
    __shared__ float row_m[32], row_l[32], row_alpha[32];

    // stage Q tile (scaled)
#pragma unroll
    for (int r = 0; r < 8; ++r) {
        int e = tid + r * 256;
        int c = e >> 3, i4 = (e & 7) << 2;
        float4 qv = *(const float4*)(qp + (size_t)c * NPIX + i0 + i4);
        ushort4 h;
        h.x = f2bf(qv.x * 0.0625f); h.y = f2bf(qv.y * 0.0625f);
        h.z = f2bf(qv.z * 0.0625f); h.w = f2bf(qv.w * 0.0625f);
        *(ushort4*)&qs[c][i4] = h;
    }
    if (tid < 32) { row_m[tid] = -1e30f; row_l[tid] = 0.0f; }

    const int pos = tid & 63, slice = tid >> 6;
    const int si4 = (pos & 7) << 2, sj4 = (pos >> 3) << 2;
    const int c0 = slice << 6;
    const int srow = tid >> 3, sjq = (tid & 7) << 2;
    const int ig = tid & 7, cg = tid >> 3;

    float acc[4][8];
#pragma unroll
    for (int ii = 0; ii < 4; ++ii)
#pragma unroll
        for (int cc = 0; cc < 8; ++cc) acc[ii][cc] = 0.0f;

    __syncthreads();

    for (int jt = 0; jt < 128; ++jt) {
        const int j0 = jt * 32;
        // ---- stage K tile ----
#pragma unroll
        for (int r = 0; r < 8; ++r) {
            int e = tid + r * 256;
            int c = e >> 3, j4 = (e & 7) << 2;
            float4 kv = *(const float4*)(kp + (size_t)c * NPIX + j0 + j4);
            ushort4 h;
            h.x = f2bf(kv.x); h.y = f2bf(kv.y);
            h.z = f2bf(kv.z); h.w = f2bf(kv.w);
            *(ushort4*)&ks[c][j4] = h;
        }
        __syncthreads();                    // (1)

        // ---- scores: each thread 4x4 tile over one 64-wide c slice ----
        {
            float sc[4][4];
#pragma unroll
            for (int ii = 0; ii < 4; ++ii)
#pragma unroll
                for (int jj = 0; jj < 4; ++jj) sc[ii][jj] = 0.0f;
#pragma unroll 4
            for (int c = c0; c < c0 + 64; ++c) {
                ushort4 qh = *(const ushort4*)&qs[c][si4];
                ushort4 kh = *(const ushort4*)&ks[c][sj4];
                float q0 = bf2f(qh.x), q1 = bf2f(qh.y), q2 = bf2f(qh.z), q3 = bf2f(qh.w);
                float k0 = bf2f(kh.x), k1 = bf2f(kh.y), k2 = bf2f(kh.z), k3 = bf2f(kh.w);
                sc[0][0] += q0 * k0; sc[0][1] += q0 * k1; sc[0][2] += q0 * k2; sc[0][3] += q0 * k3;
                sc[1][0] += q1 * k0; sc[1][1] += q1 * k1; sc[1][2] += q1 * k2; sc[1][3] += q1 * k3;
                sc[2][0] += q2 * k0; sc[2][1] += q2 * k1; sc[2][2] += q2 * k2; sc[2][3] += q2 * k3;
                sc[3][0] += q3 * k0; sc[3][1] += q3 * k1; sc[3][2] += q3 * k2; sc[3][3] += q3 * k3;
            }
#pragma unroll
            for (int ii = 0; ii < 4; ++ii) {
                float4 w4 = {sc[ii][0], sc[ii][1], sc[ii][2], sc[ii][3]};
                *(float4*)&u.ps4[slice][si4 + ii][sj4] = w4;
            }
        }
        __syncthreads();                    // (2)

        // ---- online softmax update: 8 lanes per row ----
        {
            float4 a0 = *(const float4*)&u.ps4[0][srow][sjq];
            float4 a1 = *(const float4*)&u.ps4[1][srow][sjq];
            float4 a2 = *(const float4*)&u.ps4[2][srow][sjq];
            float4 a3 = *(const float4*)&u.ps4[3][srow][sjq];
            float s0 = a0.x + a1.x + a2.x + a3.x;
            float s1 = a0.y + a1.y + a2.y + a3.y;
            float s2 = a0.z + a1.z + a2.z + a3.z;
            float s3 = a0.w + a1.w + a2.w + a3.w;
            float tm = fmaxf(fmaxf(s0, s1), fmaxf(s2, s3));
            tm = fmaxf(tm, __shfl_xor(tm, 1));
            tm = fmaxf(tm, __shfl_xor(tm, 2));
            tm = fmaxf(tm, __shfl_xor(tm, 4));
            float mold = row_m[srow];
            float mnew = fmaxf(mold, tm);
            float p0 = __expf(s0 - mnew), p1 = __expf(s1 - mnew);
            float p2 = __expf(s2 - mnew), p3 = __expf(s3 - mnew);
            float ls = p0 + p1 + p2 + p3;
            ls += __shfl_xor(ls, 1);
            ls += __shfl_xor(ls, 2);
            ls += __shfl_xor(ls, 4);
            float alpha = __expf(mold - mnew);
            ps[srow][sjq + 0] = p0; ps[srow][sjq + 1] = p1;
            ps[srow][sjq + 2] = p2; ps[srow][sjq + 3] = p3;
            if ((tid & 7) == 0) {
                row_m[srow] = mnew;
                row_l[srow] = row_l[srow] * alpha + ls;
                row_alpha[srow] = alpha;
            }
        }
        __syncthreads();                    // (3)

        // ---- stage V tile into the union region (ps4 fully consumed) ----
#pragma unroll
        for (int r = 0; r < 8; ++r) {
            int e = tid + r * 256;
            int c = e >> 3, j4 = (e & 7) << 2;
            float4 vv = *(const float4*)(vp + (size_t)c * NPIX + j0 + j4);
            u.vs[j4 + 0][c] = f2bf(vv.x);
            u.vs[j4 + 1][c] = f2bf(vv.y);
            u.vs[j4 + 2][c] = f2bf(vv.z);
            u.vs[j4 + 3][c] = f2bf(vv.w);
        }
        __syncthreads();                    // (4)

        // ---- PV accumulate: thread owns 4 i x 8 c (c strided by 32) ----
        {
            float al[4];
#pragma unroll
            for (int ii = 0; ii < 4; ++ii) al[ii] = row_alpha[ig * 4 + ii];
#pragma unroll
            for (int ii = 0; ii < 4; ++ii)
#pragma unroll
                for (int cc = 0; cc < 8; ++cc) acc[ii][cc] *= al[ii];
#pragma unroll 2
            for (int j = 0; j < 32; ++j) {
                float pvv[4];
#pragma unroll
                for (int ii = 0; ii < 4; ++ii) pvv[ii] = ps[ig * 4 + ii][j];
                float vv[8];
#pragma unroll
                for (int cc = 0; cc < 8; ++cc) vv[cc] = bf2f(u.vs[j][cg + 32 * cc]);
#pragma unroll
                for (int ii = 0; ii < 4; ++ii)
#pragma unroll
                    for (int cc = 0; cc < 8; ++cc) acc[ii][cc] += pvv[ii] * vv[cc];
            }
        }
        // no barrier needed here: next iteration's barrier (1) orders
        // PV(t) before scores(t+1) overwriting the union region.
    }

    // ---- epilogue: normalize by row_l and write h ----
    {
        float invl[4];
#pragma unroll
        for (int ii = 0; ii < 4; ++ii) invl[ii] = 1.0f / row_l[ig * 4 + ii];
        float* hp = hb + (size_t)b * CC * NPIX;
#pragma unroll
        for (int ii = 0; ii < 4; ++ii)
#pragma unroll
            for (int cc = 0; cc < 8; ++cc)
                hp[(size_t)(cg + 32 * cc) * NPIX + i0 + ig * 4 + ii] =
                    acc[ii][cc] * invl[ii];
    }
}

// ---------------- Kernel 4: output projection + bias + residual ----------------
__global__ __launch_bounds__(256) void proj_gemm(
    const float* __restrict__ hb, const float* __restrict__ wp,
    const float* __restrict__ bp, const float* __restrict__ x,
    float* __restrict__ out) {
    const int tid = threadIdx.x;
    const int n0 = blockIdx.x * 64;
    const int m = blockIdx.y;
    const int b = blockIdx.z;

    __shared__ float sS[32][64];
    __shared__ float sW[32][33];

    const int px4 = (tid & 15) << 2;
    const int ob = tid >> 4;
    float4 acc0 = {0, 0, 0, 0}, acc1 = {0, 0, 0, 0};

    for (int kt = 0; kt < 8; ++kt) {
#pragma unroll
        for (int r = 0; r < 8; ++r) {
            int e = tid + r * 256;
            int ci = e >> 6, pxl = e & 63;
            sS[ci][pxl] = hb[(size_t)(b * CC + kt * 32 + ci) * NPIX + n0 + pxl];
        }
#pragma unroll
        for (int r = 0; r < 4; ++r) {
            int e = tid + r * 256;
            int o = e >> 5, i = e & 31;
            sW[o][i] = wp[(size_t)(m * 32 + o) * CC + kt * 32 + i];
        }
        __syncthreads();
#pragma unroll 8
        for (int kk = 0; kk < 32; ++kk) {
            float4 sv = *(const float4*)&sS[kk][px4];
            float w0 = sW[ob * 2 + 0][kk];
            float w1 = sW[ob * 2 + 1][kk];
            acc0.x += w0 * sv.x; acc0.y += w0 * sv.y;
            acc0.z += w0 * sv.z; acc0.w += w0 * sv.w;
            acc1.x += w1 * sv.x; acc1.y += w1 * sv.y;
            acc1.z += w1 * sv.z; acc1.w += w1 * sv.w;
        }
        __syncthreads();
    }
    int o0 = m * 32 + ob * 2;
    size_t idx0 = (size_t)(b * CC + o0) * NPIX + n0 + px4;
    size_t idx1 = idx0 + NPIX;
    float4 x0 = *(const float4*)(x + idx0);
    float4 x1 = *(const float4*)(x + idx1);
    float b0 = bp[o0], b1 = bp[o0 + 1];
    float4 r0 = {x0.x + acc0.x + b0, x0.y + acc0.y + b0,
                 x0.z + acc0.z + b0, x0.w + acc0.w + b0};
    float4 r1 = {x1.x + acc1.x + b1, x1.y + acc1.y + b1,
                 x1.z + acc1.z + b1, x1.w + acc1.w + b1};
    *(float4*)(out + idx0) = r0;
    *(float4*)(out + idx1) = r1;
}

extern "C" void kernel_launch(void* const* d_in, const int* in_sizes, int n_in,
                              void* d_out, int out_size, void* d_ws, size_t ws_size,
                              hipStream_t stream) {
    const float* x     = (const float*)d_in[0];
    const float* gamma = (const float*)d_in[1];
    const float* beta  = (const float*)d_in[2];
    const float* wq    = (const float*)d_in[3];
    const float* bq    = (const float*)d_in[4];
    const float* wk    = (const float*)d_in[5];
    const float* bk    = (const float*)d_in[6];
    const float* wv    = (const float*)d_in[7];
    const float* bv    = (const float*)d_in[8];
    const float* wp    = (const float*)d_in[9];
    const float* bp    = (const float*)d_in[10];
    float* out = (float*)d_out;

    float* ws = (float*)d_ws;
    float* meanv = ws;                       // 128
    float* rstdv = ws + 128;                 // 128
    float* qb = ws + 1024;
    float* kb = qb + (size_t)BB * CC * NPIX;
    float* vb = kb + (size_t)BB * CC * NPIX;
    float* hb = qb;  // alias: each attn block fully consumes its q slice (into
                     // LDS at block start) before writing h to the same range.

    gn_stats<<<BB * NG, 256, 0, stream>>>(x, meanv, rstdv);
    qkv_gemm<<<dim3(64, 24, 4), 256, 0, stream>>>(x, meanv, rstdv, gamma, beta,
                                                  wq, bq, wk, bk, wv, bv,
                                                  qb, kb, vb);
    attn_flash<<<dim3(128, 4), 256, 0, stream>>>(qb, kb, vb, hb);
    proj_gemm<<<dim3(64, 8, 4), 256, 0, stream>>>(hb, wp, bp, x, out);
}

// Round 2
// 531.777 us; speedup vs baseline: 3.3085x; 3.3085x over previous
//
#include <hip/hip_runtime.h>

#define BB 4
#define CCH 256
#define NPIX 4096
#define NG 32
#define CPG 8
#define EPS 1e-6f

typedef __attribute__((ext_vector_type(8))) short bf16x8;
typedef __attribute__((ext_vector_type(4))) float f32x4;

__device__ __forceinline__ unsigned short f2bf(float f) {
    return (unsigned short)((__float_as_uint(f) + 0x8000u) >> 16);
}
__device__ __forceinline__ float bf2f(unsigned short h) {
    return __uint_as_float((unsigned)h << 16);
}
__device__ __forceinline__ void gl2lds16(const void* g, void* l) {
    __builtin_amdgcn_global_load_lds(
        (const __attribute__((address_space(1))) unsigned int*)g,
        (__attribute__((address_space(3))) unsigned int*)l, 16, 0, 0);
}

// ---------------- Kernel 1: GroupNorm statistics ----------------
__global__ __launch_bounds__(256) void gn_stats(const float* __restrict__ x,
                                                float* __restrict__ meanv,
                                                float* __restrict__ rstdv) {
    int bg = blockIdx.x;            // b*NG + g
    int b = bg >> 5, g = bg & 31;
    const float4* xb4 = (const float4*)(x + (size_t)(b * CCH + g * CPG) * NPIX);
    float s = 0.f, ss = 0.f;
    for (int e = threadIdx.x; e < CPG * NPIX / 4; e += 256) {
        float4 v = xb4[e];
        s += v.x + v.y + v.z + v.w;
        ss += v.x * v.x + v.y * v.y + v.z * v.z + v.w * v.w;
    }
    __shared__ float rs[256], rss[256];
    rs[threadIdx.x] = s; rss[threadIdx.x] = ss;
    __syncthreads();
    for (int off = 128; off > 0; off >>= 1) {
        if (threadIdx.x < (unsigned)off) {
            rs[threadIdx.x] += rs[threadIdx.x + off];
            rss[threadIdx.x] += rss[threadIdx.x + off];
        }
        __syncthreads();
    }
    if (threadIdx.x == 0) {
        const float inv = 1.0f / (float)(CPG * NPIX);
        float m = rs[0] * inv;
        float var = rss[0] * inv - m * m;
        meanv[bg] = m;
        rstdv[bg] = rsqrtf(var + EPS);
    }
}

// ------- Kernel 2: fused GroupNorm-apply + QKV 1x1 convs (bf16 outputs) -------
// qT,kT: [B][N][C] bf16 (q pre-scaled by C^-1/2); vB: [B][C][N] bf16.
__global__ __launch_bounds__(256) void qkv_gemm(
    const float* __restrict__ x, const float* __restrict__ meanv,
    const float* __restrict__ rstdv, const float* __restrict__ gamma,
    const float* __restrict__ beta,
    const float* __restrict__ wq, const float* __restrict__ bq,
    const float* __restrict__ wk, const float* __restrict__ bk,
    const float* __restrict__ wv, const float* __restrict__ bv,
    unsigned short* __restrict__ qT, unsigned short* __restrict__ kT,
    unsigned short* __restrict__ vB) {
    const int tid = threadIdx.x;
    const int n0 = blockIdx.x * 64;
    const int which = blockIdx.y >> 3;
    const int m = blockIdx.y & 7;
    const int b = blockIdx.z;
    const float* w    = (which == 0) ? wq : (which == 1) ? wk : wv;
    const float* bias = (which == 0) ? bq : (which == 1) ? bk : bv;

    __shared__ float sS[32][64];
    __shared__ float sW[32][33];

    const int px4 = (tid & 15) << 2;
    const int ob = tid >> 4;   // 0..15 -> 2 output rows each
    float4 acc0 = {0, 0, 0, 0}, acc1 = {0, 0, 0, 0};

    for (int kt = 0; kt < 8; ++kt) {
#pragma unroll
        for (int r = 0; r < 8; ++r) {
            int e = tid + r * 256;
            int ci = e >> 6, pxl = e & 63;
            int c = kt * 32 + ci;
            int bg = b * 32 + (c >> 3);
            float v = x[(size_t)(b * CCH + c) * NPIX + n0 + pxl];
            sS[ci][pxl] = (v - meanv[bg]) * rstdv[bg] * gamma[c] + beta[c];
        }
#pragma unroll
        for (int r = 0; r < 4; ++r) {
            int e = tid + r * 256;
            int o = e >> 5, i = e & 31;
            sW[o][i] = w[(size_t)(m * 32 + o) * CCH + kt * 32 + i];
        }
        __syncthreads();
#pragma unroll 8
        for (int kk = 0; kk < 32; ++kk) {
            float4 sv = *(const float4*)&sS[kk][px4];
            float w0 = sW[ob * 2 + 0][kk];
            float w1 = sW[ob * 2 + 1][kk];
            acc0.x += w0 * sv.x; acc0.y += w0 * sv.y;
            acc0.z += w0 * sv.z; acc0.w += w0 * sv.w;
            acc1.x += w1 * sv.x; acc1.y += w1 * sv.y;
            acc1.z += w1 * sv.z; acc1.w += w1 * sv.w;
        }
        __syncthreads();
    }
    int o0 = m * 32 + ob * 2;
    float b0 = bias[o0], b1 = bias[o0 + 1];
    if (which == 2) {
        ushort4 r0, r1;
        r0.x = f2bf(acc0.x + b0); r0.y = f2bf(acc0.y + b0);
        r0.z = f2bf(acc0.z + b0); r0.w = f2bf(acc0.w + b0);
        r1.x = f2bf(acc1.x + b1); r1.y = f2bf(acc1.y + b1);
        r1.z = f2bf(acc1.z + b1); r1.w = f2bf(acc1.w + b1);
        *(ushort4*)(vB + (size_t)(b * CCH + o0) * NPIX + n0 + px4) = r0;
        *(ushort4*)(vB + (size_t)(b * CCH + o0 + 1) * NPIX + n0 + px4) = r1;
    } else {
        unsigned short* qk = (which == 0) ? qT : kT;
        const float sc = (which == 0) ? 0.0625f : 1.0f;   // C^-1/2 folded into q
        float a0[4] = {acc0.x, acc0.y, acc0.z, acc0.w};
        float a1[4] = {acc1.x, acc1.y, acc1.z, acc1.w};
#pragma unroll
        for (int p = 0; p < 4; ++p) {
            unsigned lo = f2bf((a0[p] + b0) * sc);
            unsigned hi = f2bf((a1[p] + b1) * sc);
            *(unsigned*)(qk + (size_t)(b * NPIX + n0 + px4 + p) * CCH + o0) =
                lo | (hi << 16);
        }
    }
}

// ---------------- Kernel 3: MFMA flash attention ----------------
// Block = 4 waves: wave w -> i-group (w>>1, 32 rows of the 64-row Q tile),
// j-half (w&1, 32 of the 64-j K/V tile). Each wave runs an INDEPENDENT
// online softmax over its j-half; one merge in the epilogue.
// LDS 64KB exactly: K-region [0,32K) = K-tile [64j][256c] bf16 (16B-chunk
// XOR swizzle), V-region [32K,64K) = V-tile [256c][64j]. P (per-wave 2KB)
// overwrites the dead K-region after scores. Q staged once via V-region.
__global__ __launch_bounds__(256, 1) void attn_mfma(
    const unsigned short* __restrict__ qT, const unsigned short* __restrict__ kT,
    const unsigned short* __restrict__ vB, unsigned short* __restrict__ hB) {
    __shared__ __align__(16) char lds[65536];
    const int tid = threadIdx.x;
    const int lane = tid & 63;
    const int w = tid >> 6;
    const int ig = w >> 1, jh = w & 1;
    const int ln15 = lane & 15, q = lane >> 4;

    // XCD-aware swizzle: blocks of one batch land on 2 XCDs -> K/V stay in L2
    const int bx = blockIdx.x;
    const int xcd = bx & 7;
    const int b = xcd >> 1;
    const int itile = ((bx >> 3) << 1) | (xcd & 1);
    const int i0 = itile * 64;

    const size_t bqk = (size_t)b * NPIX * CCH;  // qT/kT batch offset (elems)
    const size_t bvv = (size_t)b * CCH * NPIX;  // vB batch offset

    // ---- stage Q tile [64 i][256 c] into V-region (swizzled chunks) ----
#pragma unroll
    for (int t = 0; t < 8; ++t) {
        int L = (w * 8 + t) * 64 + lane;
        int i = L >> 5, ccs = L & 31;
        int cc = ccs ^ (i & 7);
        gl2lds16(qT + bqk + (size_t)(i0 + i) * CCH + cc * 8,
                 &lds[32768 + (w * 8 + t) * 1024]);
    }
    __syncthreads();

    // ---- Q A-frags to registers: A[m=lane&15][k=quad*8+t] ----
    bf16x8 qf[2][8];
#pragma unroll
    for (int is = 0; is < 2; ++is) {
        int il = ig * 32 + is * 16 + ln15;
#pragma unroll
        for (int kb = 0; kb < 8; ++kb) {
            int cc = kb * 4 + q;
            qf[is][kb] = *(const bf16x8*)&lds[32768 + il * 512 + ((cc ^ (il & 7)) << 4)];
        }
    }
    __syncthreads();   // done with V-region before first staging

    f32x4 O[2][16];
#pragma unroll
    for (int is = 0; is < 2; ++is)
#pragma unroll
        for (int ns = 0; ns < 16; ++ns) {
            O[is][ns][0] = 0.f; O[is][ns][1] = 0.f;
            O[is][ns][2] = 0.f; O[is][ns][3] = 0.f;
        }
    float m_r[2][4], l_r[2][4];
#pragma unroll
    for (int is = 0; is < 2; ++is)
#pragma unroll
        for (int r = 0; r < 4; ++r) { m_r[is][r] = -1e30f; l_r[is][r] = 0.f; }

    const int wslot = w * 2048;

#pragma unroll 1
    for (int jt = 0; jt < 64; ++jt) {
        const int j0 = jt * 64;
        // ---- async stage K-tile and V-tile ----
#pragma unroll
        for (int t = 0; t < 8; ++t) {
            int L = (w * 8 + t) * 64 + lane;
            int j = L >> 5, ccs = L & 31;
            int cc = ccs ^ (j & 7);
            gl2lds16(kT + bqk + (size_t)(j0 + j) * CCH + cc * 8,
                     &lds[(w * 8 + t) * 1024]);
            int c = L >> 3, s = L & 7;
            int jc = s ^ (c & 7);
            gl2lds16(vB + bvv + (size_t)c * NPIX + j0 + jc * 8,
                     &lds[32768 + (w * 8 + t) * 1024]);
        }
        __syncthreads();                       // staging complete

        // ---- scores S[32 i][32 j] for this wave's (ig, jh) ----
        f32x4 S[2][2];
#pragma unroll
        for (int is = 0; is < 2; ++is)
#pragma unroll
            for (int js = 0; js < 2; ++js) {
                S[is][js][0] = 0.f; S[is][js][1] = 0.f;
                S[is][js][2] = 0.f; S[is][js][3] = 0.f;
            }
#pragma unroll
        for (int js = 0; js < 2; ++js) {
            int ja = jh * 32 + js * 16 + ln15;
#pragma unroll
            for (int kb = 0; kb < 8; ++kb) {
                int cc = kb * 4 + q;
                bf16x8 kf = *(const bf16x8*)&lds[ja * 512 + ((cc ^ (ja & 7)) << 4)];
                S[0][js] = __builtin_amdgcn_mfma_f32_16x16x32_bf16(qf[0][kb], kf, S[0][js], 0, 0, 0);
                S[1][js] = __builtin_amdgcn_mfma_f32_16x16x32_bf16(qf[1][kb], kf, S[1][js], 0, 0, 0);
            }
        }
        __syncthreads();                       // all waves done reading K-region

        // ---- online softmax (rows fully wave-local); write P into K-region ----
        float alpha[2][4];
#pragma unroll
        for (int is = 0; is < 2; ++is) {
#pragma unroll
            for (int r = 0; r < 4; ++r) {
                float s0 = S[is][0][r], s1 = S[is][1][r];
                float mx = fmaxf(s0, s1);
                mx = fmaxf(mx, __shfl_xor(mx, 1));
                mx = fmaxf(mx, __shfl_xor(mx, 2));
                mx = fmaxf(mx, __shfl_xor(mx, 4));
                mx = fmaxf(mx, __shfl_xor(mx, 8));
                float mo = m_r[is][r];
                float mn = fmaxf(mo, mx);
                float al = __expf(mo - mn);
                float p0 = __expf(s0 - mn), p1 = __expf(s1 - mn);
                float sm = p0 + p1;
                sm += __shfl_xor(sm, 1);
                sm += __shfl_xor(sm, 2);
                sm += __shfl_xor(sm, 4);
                sm += __shfl_xor(sm, 8);
                m_r[is][r] = mn;
                l_r[is][r] = l_r[is][r] * al + sm;
                alpha[is][r] = al;
                int il = is * 16 + q * 4 + r;
                int ja = ln15;          // js=0 local j
                *(unsigned short*)&lds[wslot + il * 64 + (((ja >> 3) ^ (il & 3)) << 4) + ((ja & 7) << 1)] = f2bf(p0);
                int jb = 16 + ln15;     // js=1 local j
                *(unsigned short*)&lds[wslot + il * 64 + (((jb >> 3) ^ (il & 3)) << 4) + ((jb & 7) << 1)] = f2bf(p1);
            }
        }
        asm volatile("s_waitcnt lgkmcnt(0)" ::: "memory");  // P writes -> reads (in-wave)

        // ---- P A-frags ----
        bf16x8 pf[2];
#pragma unroll
        for (int is = 0; is < 2; ++is) {
            int il = is * 16 + ln15;
            pf[is] = *(const bf16x8*)&lds[wslot + il * 64 + ((q ^ (il & 3)) << 4)];
        }

        // ---- rescale O by alpha ----
#pragma unroll
        for (int is = 0; is < 2; ++is)
#pragma unroll
            for (int ns = 0; ns < 16; ++ns) {
                O[is][ns][0] *= alpha[is][0];
                O[is][ns][1] *= alpha[is][1];
                O[is][ns][2] *= alpha[is][2];
                O[is][ns][3] *= alpha[is][3];
            }

        // ---- PV: O[32 i][256 c] += P[32 i][32 j] * V[32 j][256 c] ----
#pragma unroll
        for (int ns = 0; ns < 16; ++ns) {
            int c = ns * 16 + ln15;
            bf16x8 vf = *(const bf16x8*)&lds[32768 + c * 128 + (((jh * 4 + q) ^ (c & 7)) << 4)];
            O[0][ns] = __builtin_amdgcn_mfma_f32_16x16x32_bf16(pf[0], vf, O[0][ns], 0, 0, 0);
            O[1][ns] = __builtin_amdgcn_mfma_f32_16x16x32_bf16(pf[1], vf, O[1][ns], 0, 0, 0);
        }
        __syncthreads();                       // done with V and P
    }

    // ---- epilogue: merge the two j-half waves of each i-group ----
    if (ln15 == 0) {
#pragma unroll
        for (int is = 0; is < 2; ++is)
#pragma unroll
            for (int r = 0; r < 4; ++r) {
                int row = is * 16 + q * 4 + r;
                *(float*)&lds[w * 256 + row * 4] = m_r[is][r];
                *(float*)&lds[w * 256 + 128 + row * 4] = l_r[is][r];
            }
    }
    __syncthreads();
    const int wp = w ^ 1;
    float inv_l[2][4];
#pragma unroll
    for (int is = 0; is < 2; ++is)
#pragma unroll
        for (int r = 0; r < 4; ++r) {
            int row = is * 16 + q * 4 + r;
            float mo = m_r[is][r], lo_ = l_r[is][r];
            float mp = *(const float*)&lds[wp * 256 + row * 4];
            float lp = *(const float*)&lds[wp * 256 + 128 + row * 4];
            float ms = fmaxf(mo, mp);
            float fown = __expf(mo - ms);
            float ffar = __expf(mp - ms);
            float ls = lo_ * fown + lp * ffar;
            inv_l[is][r] = 1.0f / ls;
#pragma unroll
            for (int ns = 0; ns < 16; ++ns) O[is][ns][r] *= fown;
        }
    __syncthreads();

    const int xb = 4096 + ig * 16384;   // 16KB exchange buffer per i-group
#pragma unroll
    for (int half = 0; half < 2; ++half) {
        if (jh == 1) {
#pragma unroll
            for (int is = 0; is < 2; ++is)
#pragma unroll
                for (int n8 = 0; n8 < 8; ++n8) {
                    int ns = half * 8 + n8;
#pragma unroll
                    for (int r = 0; r < 4; ++r) {
                        int il = is * 16 + q * 4 + r;
                        *(float*)&lds[xb + ((il * 128 + n8 * 16 + ln15) << 2)] = O[is][ns][r];
                    }
                }
        }
        __syncthreads();
        if (jh == 0) {
#pragma unroll
            for (int is = 0; is < 2; ++is)
#pragma unroll
                for (int n8 = 0; n8 < 8; ++n8) {
                    int ns = half * 8 + n8;
                    int c = ns * 16 + ln15;
#pragma unroll
                    for (int r = 0; r < 4; ++r) {
                        int il = is * 16 + q * 4 + r;
                        float v = O[is][ns][r] +
                                  *(const float*)&lds[xb + ((il * 128 + n8 * 16 + ln15) << 2)];
                        hB[(size_t)(b * CCH + c) * NPIX + i0 + ig * 32 + il] =
                            f2bf(v * inv_l[is][r]);
                    }
                }
        }
        __syncthreads();
    }
}

// ---------------- Kernel 4: output projection + bias + residual ----------------
__global__ __launch_bounds__(256) void proj_gemm(
    const unsigned short* __restrict__ hB, const float* __restrict__ wp,
    const float* __restrict__ bp, const float* __restrict__ x,
    float* __restrict__ out) {
    const int tid = threadIdx.x;
    const int n0 = blockIdx.x * 64;
    const int m = blockIdx.y;
    const int b = blockIdx.z;

    __shared__ float sS[32][64];
    __shared__ float sW[32][33];

    const int px4 = (tid & 15) << 2;
    const int ob = tid >> 4;
    float4 acc0 = {0, 0, 0, 0}, acc1 = {0, 0, 0, 0};

    for (int kt = 0; kt < 8; ++kt) {
#pragma unroll
        for (int r = 0; r < 2; ++r) {
            int e = tid + r * 256;
            int ci = e >> 4, p4 = (e & 15) << 2;
            ushort4 hv = *(const ushort4*)(hB + (size_t)(b * CCH + kt * 32 + ci) * NPIX + n0 + p4);
            sS[ci][p4 + 0] = bf2f(hv.x);
            sS[ci][p4 + 1] = bf2f(hv.y);
            sS[ci][p4 + 2] = bf2f(hv.z);
            sS[ci][p4 + 3] = bf2f(hv.w);
        }
#pragma unroll
        for (int r = 0; r < 4; ++r) {
            int e = tid + r * 256;
            int o = e >> 5, i = e & 31;
            sW[o][i] = wp[(size_t)(m * 32 + o) * CCH + kt * 32 + i];
        }
        __syncthreads();
#pragma unroll 8
        for (int kk = 0; kk < 32; ++kk) {
            float4 sv = *(const float4*)&sS[kk][px4];
            float w0 = sW[ob * 2 + 0][kk];
            float w1 = sW[ob * 2 + 1][kk];
            acc0.x += w0 * sv.x; acc0.y += w0 * sv.y;
            acc0.z += w0 * sv.z; acc0.w += w0 * sv.w;
            acc1.x += w1 * sv.x; acc1.y += w1 * sv.y;
            acc1.z += w1 * sv.z; acc1.w += w1 * sv.w;
        }
        __syncthreads();
    }
    int o0 = m * 32 + ob * 2;
    size_t idx0 = (size_t)(b * CCH + o0) * NPIX + n0 + px4;
    size_t idx1 = idx0 + NPIX;
    float4 x0 = *(const float4*)(x + idx0);
    float4 x1 = *(const float4*)(x + idx1);
    float b0 = bp[o0], b1 = bp[o0 + 1];
    float4 r0 = {x0.x + acc0.x + b0, x0.y + acc0.y + b0,
                 x0.z + acc0.z + b0, x0.w + acc0.w + b0};
    float4 r1 = {x1.x + acc1.x + b1, x1.y + acc1.y + b1,
                 x1.z + acc1.z + b1, x1.w + acc1.w + b1};
    *(float4*)(out + idx0) = r0;
    *(float4*)(out + idx1) = r1;
}

extern "C" void kernel_launch(void* const* d_in, const int* in_sizes, int n_in,
                              void* d_out, int out_size, void* d_ws, size_t ws_size,
                              hipStream_t stream) {
    const float* x     = (const float*)d_in[0];
    const float* gamma = (const float*)d_in[1];
    const float* beta  = (const float*)d_in[2];
    const float* wq    = (const float*)d_in[3];
    const float* bq    = (const float*)d_in[4];
    const float* wk    = (const float*)d_in[5];
    const float* bk    = (const float*)d_in[6];
    const float* wv    = (const float*)d_in[7];
    const float* bv    = (const float*)d_in[8];
    const float* wp    = (const float*)d_in[9];
    const float* bp    = (const float*)d_in[10];
    float* out = (float*)d_out;

    char* wsb = (char*)d_ws;
    float* meanv = (float*)wsb;                    // 512 B
    float* rstdv = (float*)(wsb + 512);            // 512 B
    unsigned short* qT = (unsigned short*)(wsb + 1024);       // [B][N][C] bf16
    unsigned short* kT = qT + (size_t)BB * NPIX * CCH;        // [B][N][C] bf16
    unsigned short* vB = kT + (size_t)BB * NPIX * CCH;        // [B][C][N] bf16
    unsigned short* hB = vB + (size_t)BB * CCH * NPIX;        // [B][C][N] bf16

    gn_stats<<<BB * NG, 256, 0, stream>>>(x, meanv, rstdv);
    qkv_gemm<<<dim3(64, 24, 4), 256, 0, stream>>>(x, meanv, rstdv, gamma, beta,
                                                  wq, bq, wk, bk, wv, bv,
                                                  qT, kT, vB);
    attn_mfma<<<256, 256, 0, stream>>>(qT, kT, vB, hB);
    proj_gemm<<<dim3(64, 8, 4), 256, 0, stream>>>(hB, wp, bp, x, out);
}

// Round 3
// 264.605 us; speedup vs baseline: 6.6490x; 2.0097x over previous
//
#include <hip/hip_runtime.h>

#define BB 4
#define CCH 256
#define NPIX 4096
#define EPS 1e-6f

typedef __attribute__((ext_vector_type(8))) short bf16x8;
typedef __attribute__((ext_vector_type(4))) float f32x4;

__device__ __forceinline__ unsigned short f2bf(float f) {
    return (unsigned short)((__float_as_uint(f) + 0x8000u) >> 16);
}
__device__ __forceinline__ float bf2f(unsigned short h) {
    return __uint_as_float((unsigned)h << 16);
}
__device__ __forceinline__ void gl2lds16(const void* g, void* l) {
    __builtin_amdgcn_global_load_lds(
        (const __attribute__((address_space(1))) unsigned int*)g,
        (__attribute__((address_space(3))) unsigned int*)l, 16, 0, 0);
}

// ------- Kernel 1: GroupNorm stats + apply, writes sb[n][c] bf16 -------
__global__ __launch_bounds__(256) void gn_apply(const float* __restrict__ x,
                                                const float* __restrict__ gamma,
                                                const float* __restrict__ beta,
                                                unsigned short* __restrict__ sb) {
    int bg = blockIdx.x;            // b*32 + g
    int b = bg >> 5, g = bg & 31;
    const float4* x4 = (const float4*)(x + (size_t)(b * CCH + g * 8) * NPIX);
    float s = 0.f, ss = 0.f;
    for (int e = threadIdx.x; e < 8 * NPIX / 4; e += 256) {
        float4 v = x4[e];
        s += v.x + v.y + v.z + v.w;
        ss += v.x * v.x + v.y * v.y + v.z * v.z + v.w * v.w;
    }
    __shared__ float rs[256], rss[256];
    __shared__ float mean_s, rstd_s;
    rs[threadIdx.x] = s; rss[threadIdx.x] = ss;
    __syncthreads();
    for (int off = 128; off > 0; off >>= 1) {
        if (threadIdx.x < (unsigned)off) {
            rs[threadIdx.x] += rs[threadIdx.x + off];
            rss[threadIdx.x] += rss[threadIdx.x + off];
        }
        __syncthreads();
    }
    if (threadIdx.x == 0) {
        const float inv = 1.0f / (float)(8 * NPIX);
        float m = rs[0] * inv;
        float var = rss[0] * inv - m * m;
        mean_s = m;
        rstd_s = rsqrtf(var + EPS);
    }
    __syncthreads();
    float scale[8], shift[8];
#pragma unroll
    for (int ci = 0; ci < 8; ++ci) {
        float ga = gamma[g * 8 + ci], be = beta[g * 8 + ci];
        scale[ci] = rstd_s * ga;
        shift[ci] = be - mean_s * scale[ci];
    }
#pragma unroll 1
    for (int r = 0; r < 4; ++r) {
        int pq = r * 256 + threadIdx.x;          // pixel-quad 0..1023
        __align__(16) unsigned short h[4][8];
#pragma unroll
        for (int ci = 0; ci < 8; ++ci) {
            float4 v = x4[ci * 1024 + pq];
            h[0][ci] = f2bf(v.x * scale[ci] + shift[ci]);
            h[1][ci] = f2bf(v.y * scale[ci] + shift[ci]);
            h[2][ci] = f2bf(v.z * scale[ci] + shift[ci]);
            h[3][ci] = f2bf(v.w * scale[ci] + shift[ci]);
        }
        size_t base = ((size_t)(b * NPIX + pq * 4) << 8) + g * 8;
#pragma unroll
        for (int p = 0; p < 4; ++p)
            *(uint4*)(sb + base + (size_t)p * 256) = *(const uint4*)h[p];
    }
}

// ------- Kernel 2: weights fp32 -> bf16 (order: p, q, k, v) -------
__global__ __launch_bounds__(256) void wcvt(const float* __restrict__ wq,
                                            const float* __restrict__ wk,
                                            const float* __restrict__ wv,
                                            const float* __restrict__ wp,
                                            unsigned short* __restrict__ wb) {
    int e = blockIdx.x * 256 + threadIdx.x;      // float4 index, 0..16383
    const float* srcs[4] = {wp, wq, wk, wv};
#pragma unroll
    for (int m = 0; m < 4; ++m) {
        float4 v = ((const float4*)srcs[m])[e];
        ushort4 h;
        h.x = f2bf(v.x); h.y = f2bf(v.y); h.z = f2bf(v.z); h.w = f2bf(v.w);
        *(ushort4*)(wb + (size_t)m * 65536 + (size_t)e * 4) = h;
    }
}

// ------- Kernel 3: QKV MFMA GEMM -------
// C[n][co] = sum_c sb[n][c] * w[co][c]; block tile 128n x 128co, BK=64.
// z: 0=q (scaled, ->qT[n][c]), 1=k (->kT[n][c]), 2=v (->vB[c][n]).
__global__ __launch_bounds__(256) void qkv_mfma(
    const unsigned short* __restrict__ sb, const unsigned short* __restrict__ wb,
    const float* __restrict__ bq, const float* __restrict__ bk,
    const float* __restrict__ bv,
    unsigned short* __restrict__ qT, unsigned short* __restrict__ kT,
    unsigned short* __restrict__ vB) {
    __shared__ __align__(16) char lds[34816];
    const int tid = threadIdx.x, lane = tid & 63, w = tid >> 6;
    const int ln15 = lane & 15, q = lane >> 4;
    const int n0 = blockIdx.x * 128;
    const int co0 = blockIdx.y * 128;
    const int z = blockIdx.z;
    const unsigned short* wm = wb + (size_t)(z + 1) * 65536;
    const float* bias = (z == 0) ? bq : (z == 1) ? bk : bv;

    f32x4 acc[2][8];
#pragma unroll
    for (int i2 = 0; i2 < 2; ++i2)
#pragma unroll
        for (int nf = 0; nf < 8; ++nf) {
            acc[i2][nf][0] = 0.f; acc[i2][nf][1] = 0.f;
            acc[i2][nf][2] = 0.f; acc[i2][nf][3] = 0.f;
        }

#pragma unroll 1
    for (int kt = 0; kt < 4; ++kt) {
#pragma unroll
        for (int r = 0; r < 4; ++r) {
            int gch = r * 256 + tid;
            int row = gch >> 3, sidx = gch & 7;
            int cc = sidx ^ (row & 7);
            gl2lds16(sb + ((size_t)(n0 + row) << 8) + kt * 64 + cc * 8,
                     &lds[r * 4096 + w * 1024]);
            gl2lds16(wm + ((size_t)(co0 + row) << 8) + kt * 64 + cc * 8,
                     &lds[16384 + r * 4096 + w * 1024]);
        }
        __syncthreads();
#pragma unroll
        for (int kk = 0; kk < 2; ++kk) {
            int kc = kk * 4 + q;
            bf16x8 af[2], bf[8];
#pragma unroll
            for (int i2 = 0; i2 < 2; ++i2) {
                int row = w * 32 + i2 * 16 + ln15;
                af[i2] = *(const bf16x8*)&lds[row * 128 + ((kc ^ (row & 7)) << 4)];
            }
#pragma unroll
            for (int nf = 0; nf < 8; ++nf) {
                int row = nf * 16 + ln15;
                bf[nf] = *(const bf16x8*)&lds[16384 + row * 128 + ((kc ^ (row & 7)) << 4)];
            }
#pragma unroll
            for (int i2 = 0; i2 < 2; ++i2)
#pragma unroll
                for (int nf = 0; nf < 8; ++nf)
                    acc[i2][nf] = __builtin_amdgcn_mfma_f32_16x16x32_bf16(
                        af[i2], bf[nf], acc[i2][nf], 0, 0, 0);
        }
        __syncthreads();
    }

    // epilogue: bias (+scale for q), bounce through LDS tile for coalescing
    float bias_l[8];
#pragma unroll
    for (int nf = 0; nf < 8; ++nf) bias_l[nf] = bias[co0 + nf * 16 + ln15];
    const float scl = (z == 0) ? 0.0625f : 1.0f;
    unsigned short* T = (unsigned short*)lds;
    if (z < 2) {
#pragma unroll
        for (int i2 = 0; i2 < 2; ++i2)
#pragma unroll
            for (int nf = 0; nf < 8; ++nf)
#pragma unroll
                for (int r = 0; r < 4; ++r) {
                    int n_l = w * 32 + i2 * 16 + q * 4 + r;
                    int co_l = nf * 16 + ln15;
                    T[n_l * 136 + co_l] = f2bf((acc[i2][nf][r] + bias_l[nf]) * scl);
                }
    } else {
#pragma unroll
        for (int i2 = 0; i2 < 2; ++i2)
#pragma unroll
            for (int nf = 0; nf < 8; ++nf)
#pragma unroll
                for (int r = 0; r < 4; ++r) {
                    int n_l = w * 32 + i2 * 16 + q * 4 + r;
                    int co_l = nf * 16 + ln15;
                    T[co_l * 136 + n_l] = f2bf(acc[i2][nf][r] + bias_l[nf]);
                }
    }
    __syncthreads();
    int row = tid >> 1, half = tid & 1;
    const uint4* src = (const uint4*)&T[row * 136 + half * 64];
    uint4* dst;
    if (z < 2) {
        unsigned short* qk = (z == 0) ? qT : kT;
        dst = (uint4*)(qk + ((size_t)(n0 + row) << 8) + co0 + half * 64);
    } else {
        int b2 = n0 >> 12, pix0 = n0 & 4095;
        dst = (uint4*)(vB + ((size_t)(b2 * CCH + co0 + row) << 12) + pix0 + half * 64);
    }
#pragma unroll
    for (int u = 0; u < 8; ++u) dst[u] = src[u];
}

// ------- Kernel 4: MFMA flash attention, j-split across blocks -------
// Block: (itile 64 i-rows, b, jh half of j). 4 waves, wave w owns i rows
// [w*16, w*16+16), full 64-j tile. Writes unnormalized partial O + (m,l).
__global__ __launch_bounds__(256, 2) void attn_mfma(
    const unsigned short* __restrict__ qT, const unsigned short* __restrict__ kT,
    const unsigned short* __restrict__ vB,
    unsigned short* __restrict__ pO, float* __restrict__ pml) {
    __shared__ __align__(16) char lds[65536];
    const int tid = threadIdx.x, lane = tid & 63, w = tid >> 6;
    const int ln15 = lane & 15, q = lane >> 4;
    const int bx = blockIdx.x;
    const int jh = bx & 1, b = (bx >> 1) & 3;
    const int itile = bx >> 3;
    const int i0 = itile * 64;
    const int jbase = jh * 2048;
    const size_t nb = (size_t)b * NPIX;
    const int wslot = w * 2048;

    // ---- stage Q [64 i][256 c] into K region ----
#pragma unroll
    for (int t = 0; t < 8; ++t) {
        int gch = (w * 8 + t) * 64 + lane;
        int row = gch >> 5, sc = gch & 31;
        int cc = sc ^ (row & 7);
        gl2lds16(qT + ((nb + i0 + row) << 8) + cc * 8, &lds[(w * 8 + t) * 1024]);
    }
    __syncthreads();
    bf16x8 qf[8];
    {
        int row = w * 16 + ln15;
#pragma unroll
        for (int kb = 0; kb < 8; ++kb)
            qf[kb] = *(const bf16x8*)&lds[row * 512 + (((kb * 4 + q) ^ (row & 7)) << 4)];
    }
    __syncthreads();

    f32x4 O[16];
#pragma unroll
    for (int ns = 0; ns < 16; ++ns) {
        O[ns][0] = 0.f; O[ns][1] = 0.f; O[ns][2] = 0.f; O[ns][3] = 0.f;
    }
    float m_r[4], l_r[4];
#pragma unroll
    for (int r = 0; r < 4; ++r) { m_r[r] = -1e30f; l_r[r] = 0.f; }

#pragma unroll 1
    for (int jt = 0; jt < 32; ++jt) {
        const int j0 = jbase + jt * 64;
        // ---- stage K [64j][256c] and V [256c][64j] ----
#pragma unroll
        for (int t = 0; t < 8; ++t) {
            int gch = (w * 8 + t) * 64 + lane;
            int row = gch >> 5, sc = gch & 31;
            int cc = sc ^ (row & 7);
            gl2lds16(kT + ((nb + j0 + row) << 8) + cc * 8, &lds[(w * 8 + t) * 1024]);
            int c = gch >> 3, sv = gch & 7;
            int jc = sv ^ (c & 7);
            gl2lds16(vB + ((size_t)(b * CCH + c) << 12) + j0 + jc * 8,
                     &lds[32768 + (w * 8 + t) * 1024]);
        }
        __syncthreads();                         // (1) staging complete

        // ---- scores S[16 i][64 j] ----
        f32x4 S[4];
#pragma unroll
        for (int js = 0; js < 4; ++js) {
            S[js][0] = 0.f; S[js][1] = 0.f; S[js][2] = 0.f; S[js][3] = 0.f;
        }
#pragma unroll
        for (int js = 0; js < 4; ++js) {
            int jr = js * 16 + ln15;
#pragma unroll
            for (int kb = 0; kb < 8; ++kb) {
                bf16x8 kf = *(const bf16x8*)&lds[jr * 512 + (((kb * 4 + q) ^ (jr & 7)) << 4)];
                S[js] = __builtin_amdgcn_mfma_f32_16x16x32_bf16(qf[kb], kf, S[js], 0, 0, 0);
            }
        }
        __syncthreads();                         // (2) all waves done reading K

        // ---- online softmax; P -> per-wave slot in (dead) K region ----
        float alpha[4];
#pragma unroll
        for (int r = 0; r < 4; ++r) {
            float s0 = S[0][r], s1 = S[1][r], s2 = S[2][r], s3 = S[3][r];
            float mx = fmaxf(fmaxf(s0, s1), fmaxf(s2, s3));
            mx = fmaxf(mx, __shfl_xor(mx, 1));
            mx = fmaxf(mx, __shfl_xor(mx, 2));
            mx = fmaxf(mx, __shfl_xor(mx, 4));
            mx = fmaxf(mx, __shfl_xor(mx, 8));
            float mo = m_r[r];
            float mn = fmaxf(mo, mx);
            float p0 = __expf(s0 - mn), p1 = __expf(s1 - mn);
            float p2 = __expf(s2 - mn), p3 = __expf(s3 - mn);
            float sm = p0 + p1 + p2 + p3;
            sm += __shfl_xor(sm, 1);
            sm += __shfl_xor(sm, 2);
            sm += __shfl_xor(sm, 4);
            sm += __shfl_xor(sm, 8);
            float al = __expf(mo - mn);
            m_r[r] = mn;
            l_r[r] = l_r[r] * al + sm;
            alpha[r] = al;
            int il = q * 4 + r;
            float pv[4] = {p0, p1, p2, p3};
#pragma unroll
            for (int js = 0; js < 4; ++js) {
                int j = js * 16 + ln15;
                *(unsigned short*)&lds[wslot + il * 128 +
                    (((j >> 3) ^ (il & 7)) << 4) + ((j & 7) << 1)] = f2bf(pv[js]);
            }
        }
        asm volatile("s_waitcnt lgkmcnt(0)" ::: "memory");  // in-wave P visibility

        bf16x8 pf[2];
#pragma unroll
        for (int kf2 = 0; kf2 < 2; ++kf2)
            pf[kf2] = *(const bf16x8*)&lds[wslot + ln15 * 128 +
                                           (((kf2 * 4 + q) ^ (ln15 & 7)) << 4)];
        // rescale O
#pragma unroll
        for (int ns = 0; ns < 16; ++ns) {
            O[ns][0] *= alpha[0]; O[ns][1] *= alpha[1];
            O[ns][2] *= alpha[2]; O[ns][3] *= alpha[3];
        }
        // ---- PV: O[16 i][256 c] += P[16 i][64 j] V[64 j][256 c] ----
#pragma unroll
        for (int ns = 0; ns < 16; ++ns) {
            int c = ns * 16 + ln15;
            bf16x8 vf0 = *(const bf16x8*)&lds[32768 + c * 128 + ((q ^ (c & 7)) << 4)];
            bf16x8 vf1 = *(const bf16x8*)&lds[32768 + c * 128 + (((4 + q) ^ (c & 7)) << 4)];
            O[ns] = __builtin_amdgcn_mfma_f32_16x16x32_bf16(pf[0], vf0, O[ns], 0, 0, 0);
            O[ns] = __builtin_amdgcn_mfma_f32_16x16x32_bf16(pf[1], vf1, O[ns], 0, 0, 0);
        }
        __syncthreads();                         // (3) done with V & P
    }

    // ---- epilogue: unnormalized partial O (bf16) + m,l ----
    size_t pbase = (size_t)bx * (64 * 256);
#pragma unroll
    for (int ns = 0; ns < 16; ++ns) {
        int c = ns * 16 + ln15;
#pragma unroll
        for (int r = 0; r < 4; ++r) {
            int i = w * 16 + q * 4 + r;
            pO[pbase + i * 256 + c] = f2bf(O[ns][r]);
        }
    }
    if (ln15 == 0) {
#pragma unroll
        for (int r = 0; r < 4; ++r) {
            int i = w * 16 + q * 4 + r;
            pml[bx * 128 + i] = m_r[r];
            pml[bx * 128 + 64 + i] = l_r[r];
        }
    }
}

// ------- Kernel 5: merge the two j-half partials -> hN[n][c] bf16 -------
__global__ __launch_bounds__(256) void attn_merge(
    const unsigned short* __restrict__ pO, const float* __restrict__ pml,
    unsigned short* __restrict__ hN) {
    int bid = blockIdx.x;
    int b = bid & 3, itile = bid >> 2;
    int bx0 = (itile << 3) | (b << 1), bx1 = bx0 | 1;
    __shared__ float f0s[64], f1s[64];
    int t = threadIdx.x;
    if (t < 64) {
        float m0 = pml[bx0 * 128 + t], l0 = pml[bx0 * 128 + 64 + t];
        float m1 = pml[bx1 * 128 + t], l1 = pml[bx1 * 128 + 64 + t];
        float ms = fmaxf(m0, m1);
        float e0 = __expf(m0 - ms), e1 = __expf(m1 - ms);
        float inv = 1.0f / (l0 * e0 + l1 * e1);
        f0s[t] = e0 * inv; f1s[t] = e1 * inv;
    }
    __syncthreads();
    const unsigned short* p0 = pO + (size_t)bx0 * 16384;
    const unsigned short* p1 = pO + (size_t)bx1 * 16384;
    int i = t >> 2, cq = t & 3;
    float f0 = f0s[i], f1 = f1s[i];
    size_t nrow = ((size_t)(b * NPIX + itile * 64 + i)) << 8;
#pragma unroll
    for (int p = 0; p < 16; ++p) {
        int c = p * 16 + cq * 4;
        ushort4 a = *(const ushort4*)&p0[i * 256 + c];
        ushort4 bb = *(const ushort4*)&p1[i * 256 + c];
        ushort4 h;
        h.x = f2bf(bf2f(a.x) * f0 + bf2f(bb.x) * f1);
        h.y = f2bf(bf2f(a.y) * f0 + bf2f(bb.y) * f1);
        h.z = f2bf(bf2f(a.z) * f0 + bf2f(bb.z) * f1);
        h.w = f2bf(bf2f(a.w) * f0 + bf2f(bb.w) * f1);
        *(ushort4*)&hN[nrow + c] = h;
    }
}

// ------- Kernel 6: proj MFMA GEMM + bias + residual -> out fp32 -------
__global__ __launch_bounds__(256) void proj_mfma(
    const unsigned short* __restrict__ hN, const unsigned short* __restrict__ wb,
    const float* __restrict__ bp, const float* __restrict__ x,
    float* __restrict__ out) {
    __shared__ __align__(16) char lds[34816];
    const int tid = threadIdx.x, lane = tid & 63, w = tid >> 6;
    const int ln15 = lane & 15, q = lane >> 4;
    const int n0 = blockIdx.x * 128;
    const int co0 = blockIdx.y * 128;

    f32x4 acc[2][8];
#pragma unroll
    for (int i2 = 0; i2 < 2; ++i2)
#pragma unroll
        for (int nf = 0; nf < 8; ++nf) {
            acc[i2][nf][0] = 0.f; acc[i2][nf][1] = 0.f;
            acc[i2][nf][2] = 0.f; acc[i2][nf][3] = 0.f;
        }

#pragma unroll 1
    for (int kt = 0; kt < 4; ++kt) {
#pragma unroll
        for (int r = 0; r < 4; ++r) {
            int gch = r * 256 + tid;
            int row = gch >> 3, sidx = gch & 7;
            int cc = sidx ^ (row & 7);
            gl2lds16(hN + ((size_t)(n0 + row) << 8) + kt * 64 + cc * 8,
                     &lds[r * 4096 + w * 1024]);
            gl2lds16(wb + ((size_t)(co0 + row) << 8) + kt * 64 + cc * 8,
                     &lds[16384 + r * 4096 + w * 1024]);
        }
        __syncthreads();
#pragma unroll
        for (int kk = 0; kk < 2; ++kk) {
            int kc = kk * 4 + q;
            bf16x8 af[2], bf[8];
#pragma unroll
            for (int i2 = 0; i2 < 2; ++i2) {
                int row = w * 32 + i2 * 16 + ln15;
                af[i2] = *(const bf16x8*)&lds[row * 128 + ((kc ^ (row & 7)) << 4)];
            }
#pragma unroll
            for (int nf = 0; nf < 8; ++nf) {
                int row = nf * 16 + ln15;
                bf[nf] = *(const bf16x8*)&lds[16384 + row * 128 + ((kc ^ (row & 7)) << 4)];
            }
#pragma unroll
            for (int i2 = 0; i2 < 2; ++i2)
#pragma unroll
                for (int nf = 0; nf < 8; ++nf)
                    acc[i2][nf] = __builtin_amdgcn_mfma_f32_16x16x32_bf16(
                        af[i2], bf[nf], acc[i2][nf], 0, 0, 0);
        }
        __syncthreads();
    }

    unsigned short* T = (unsigned short*)lds;
#pragma unroll
    for (int i2 = 0; i2 < 2; ++i2)
#pragma unroll
        for (int nf = 0; nf < 8; ++nf)
#pragma unroll
            for (int r = 0; r < 4; ++r) {
                int n_l = w * 32 + i2 * 16 + q * 4 + r;
                int co_l = nf * 16 + ln15;
                T[co_l * 136 + n_l] = f2bf(acc[i2][nf][r]);
            }
    __syncthreads();
    int row = tid >> 1, half = tid & 1;       // row = co_local
    int b2 = n0 >> 12, pix0 = n0 & 4095;
    float br = bp[co0 + row];
    size_t gidx = (((size_t)(b2 * CCH + co0 + row)) << 12) + pix0 + half * 64;
    const unsigned short* trow = &T[row * 136 + half * 64];
#pragma unroll
    for (int u = 0; u < 16; ++u) {
        float4 xv = *(const float4*)&x[gidx + u * 4];
        ushort4 tv = *(const ushort4*)&trow[u * 4];
        float4 o;
        o.x = xv.x + br + bf2f(tv.x);
        o.y = xv.y + br + bf2f(tv.y);
        o.z = xv.z + br + bf2f(tv.z);
        o.w = xv.w + br + bf2f(tv.w);
        *(float4*)&out[gidx + u * 4] = o;
    }
}

extern "C" void kernel_launch(void* const* d_in, const int* in_sizes, int n_in,
                              void* d_out, int out_size, void* d_ws, size_t ws_size,
                              hipStream_t stream) {
    const float* x     = (const float*)d_in[0];
    const float* gamma = (const float*)d_in[1];
    const float* beta  = (const float*)d_in[2];
    const float* wq    = (const float*)d_in[3];
    const float* bq    = (const float*)d_in[4];
    const float* wk    = (const float*)d_in[5];
    const float* bk    = (const float*)d_in[6];
    const float* wv    = (const float*)d_in[7];
    const float* bv    = (const float*)d_in[8];
    const float* wp    = (const float*)d_in[9];
    const float* bp    = (const float*)d_in[10];
    float* out = (float*)d_out;

    char* wsb = (char*)d_ws;
    // sb (GN output, consumed by qkv_mfma) aliases hN (written by attn_merge
    // afterwards) — stream-ordered, safe.
    unsigned short* sb  = (unsigned short*)wsb;                    //  8 MB
    unsigned short* hN  = sb;                                      //  alias
    unsigned short* wb  = (unsigned short*)(wsb + 8388608);        // 512 KB
    unsigned short* pO  = (unsigned short*)(wsb + 8912896);        // 16 MB
    float*          pml = (float*)(wsb + 25690112);                // 256 KB
    unsigned short* qT  = (unsigned short*)(wsb + 25952256);       //  8 MB
    unsigned short* kT  = (unsigned short*)(wsb + 34340864);       //  8 MB
    unsigned short* vB  = (unsigned short*)(wsb + 42729472);       //  8 MB

    gn_apply<<<BB * 32, 256, 0, stream>>>(x, gamma, beta, sb);
    wcvt<<<64, 256, 0, stream>>>(wq, wk, wv, wp, wb);
    qkv_mfma<<<dim3(128, 2, 3), 256, 0, stream>>>(sb, wb, bq, bk, bv, qT, kT, vB);
    attn_mfma<<<512, 256, 0, stream>>>(qT, kT, vB, pO, pml);
    attn_merge<<<256, 256, 0, stream>>>(pO, pml, hN);
    proj_mfma<<<dim3(128, 2), 256, 0, stream>>>(hN, wb, bp, x, out);
}